// Round 11
// baseline (413.711 us; speedup 1.0000x reference)
//
#include <hip/hip_runtime.h>
#include <cstddef>

#define CCH 768
#define CHUNK 262144u

// ---- d_out scratch carve (256 KiB chunks) — EXACT R10 layout ----
// tail [0,170): Yt(f32,96) Hh(48) W2T(18) aux+partial  -> final memcpy
// [170,227)  Xl, GWh, GWl (dead after gate)            -> restored in exp1
// [227,293)  Xh, W1T (dead after exp1)                 -> restored in exp2
// early s4 [293,768) + s8 [768,1002)                   -> restored in gate
// s8 [1002,1077) + s16 [1152,1248)                     -> restored in exp1
// s8 [1077,1152) + s16 [1248,1344)                     -> restored in exp2
#define OFF_YT    0u
#define OFF_HH    25165824u
#define OFF_W2T   37748736u
#define OFF_AUX   42467328u
#define OFF_PART  42631424u
#define TAILBYTES 44564480u
#define OFF_XL    44564480u
#define OFF_GWH   57147392u
#define OFF_GWL   58327040u
#define OFF_XH    59506688u
#define OFF_W1T   72089600u

typedef __attribute__((ext_vector_type(8))) short short8v;
typedef __attribute__((ext_vector_type(4))) float f32x4;

__device__ __forceinline__ void gl16(const void* g, void* l) {
    __builtin_amdgcn_global_load_lds(
        (const __attribute__((address_space(1))) void*)g,
        (__attribute__((address_space(3))) void*)l, 16, 0, 0);
}

__device__ __forceinline__ void copy_chunk(int g, const char* s4b, const char* s8b,
                                           const char* s16b, char* bb) {
    const char* src = (g < 768) ? s4b + (size_t)g * CHUNK
                    : (g < 1152) ? s8b + (size_t)(g - 768) * CHUNK
                                 : s16b + (size_t)(g - 1152) * CHUNK;
    const uint4* s = (const uint4*)src;
    uint4* d = (uint4*)(bb + (size_t)g * CHUNK);
    int t = threadIdx.x;
#pragma unroll 8
    for (int it = 0; it < 64; ++it) d[it * 256 + t] = s[it * 256 + t];
}

__device__ __forceinline__ float gelu_tanh(float x) {
    // JAX default gelu (approximate=True)
    float u = 0.7978845608028654f * (x + 0.044715f * x * x * x);
    float e = __expf(2.0f * u);
    float t = 1.0f - 2.0f / (e + 1.0f);
    return 0.5f * x * (1.0f + t);
}

__device__ __forceinline__ short f2b(float f) {
    unsigned u = __float_as_uint(f);
    unsigned r = (u + 0x7FFFu + ((u >> 16) & 1u)) >> 16;
    return (short)r;
}

__device__ __forceinline__ float b2f(short s) {
    return __uint_as_float(((unsigned)(unsigned short)s) << 16);
}

// z<8: BCHW->token-major bf16 hi/lo transpose of s32. z==8: gate W1 hi/lo
// transposed convert. Also zeroes counts (which double as scatter cursors).
__global__ __launch_bounds__(256) void k_prep(const float* __restrict__ s32,
                                              const float* __restrict__ gw1,
                                              short* __restrict__ Xh,
                                              short* __restrict__ Xl,
                                              short* __restrict__ GWh,
                                              short* __restrict__ GWl,
                                              int* __restrict__ az) {
    int z = blockIdx.z;
    int tx = threadIdx.x, ty = threadIdx.y;
    if (z == 0 && blockIdx.x == 0 && blockIdx.y == 0 && ty == 0 && tx < 8)
        az[tx] = 0;
    __shared__ float tile[32][33];
    if (z < 8) {
        int c0 = blockIdx.y * 32, hw0 = blockIdx.x * 32;
        const float* s = s32 + (size_t)z * CCH * 1024;
#pragma unroll
        for (int i = 0; i < 4; ++i)
            tile[ty + 8 * i][tx] = s[(size_t)(c0 + ty + 8 * i) * 1024 + hw0 + tx];
        __syncthreads();
#pragma unroll
        for (int i = 0; i < 4; ++i) {
            int r = ty + 8 * i;
            int n = z * 1024 + hw0 + r;
            float v = tile[tx][r];
            short h = f2b(v);
            Xh[(size_t)n * CCH + c0 + tx] = h;
            Xl[(size_t)n * CCH + c0 + tx] = f2b(v - b2f(h));
        }
    } else {
        if (blockIdx.x >= 24) return;
        int ci0 = blockIdx.x * 32, co0 = blockIdx.y * 32;
#pragma unroll
        for (int i = 0; i < 4; ++i)
            tile[ty + 8 * i][tx] = gw1[(size_t)(ci0 + ty + 8 * i) * CCH + co0 + tx];
        __syncthreads();
#pragma unroll
        for (int i = 0; i < 4; ++i) {
            int co = co0 + ty + 8 * i;
            float v = tile[tx][ty + 8 * i];
            short h = f2b(v);
            GWh[(size_t)co * CCH + ci0 + tx] = h;
            GWl[(size_t)co * CCH + ci0 + tx] = f2b(v - b2f(h));
        }
    }
}

// 128x128-tile bf16 MFMA GEMM, 4 waves (64x64 quadrants), 2-phase
// double-buffered global_load_lds pipeline (R6/R10-proven core). Appended copy
// chunks per mode; MODE 0 additionally carries 4608 expert-weight converts.
// MODE 0: split-bf16: partial logits = gelu((Xh+Xl)@(GWh+GWl)^T + gb1) @ W2
// MODE 1: Hh[ofs+p] = f2b(gelu(Xh[perm_e] @ W1T^T + eb1))
// MODE 2: Yt[perm_e[p]] = (Hh @ W2T^T + eb2)*gval   (f32 token-major)
template <int MODE>
__global__ __launch_bounds__(256) void k_mfma(const short* __restrict__ Ahp,
                                              const short* __restrict__ Alp,
                                              const short* __restrict__ Bhp,
                                              const short* __restrict__ Blp,
                                              const float* __restrict__ bias,
                                              const float* __restrict__ gw2,
                                              const int* __restrict__ perm,
                                              const int* __restrict__ counts,
                                              const float* __restrict__ gval,
                                              float* __restrict__ Yt,
                                              short* __restrict__ Hout,
                                              float* __restrict__ partial,
                                              const float* __restrict__ ew1,
                                              const float* __restrict__ ew2,
                                              short* __restrict__ W1T,
                                              short* __restrict__ W2T,
                                              const char* __restrict__ s4b,
                                              const char* __restrict__ s8b,
                                              const char* __restrict__ s16b,
                                              char* __restrict__ bb,
                                              int ngemm, int ncopy) {
    __shared__ __align__(16) short lds[32768];
    int bid = blockIdx.x;
    int t = threadIdx.x;
    if (bid >= ngemm) {
        int i = bid - ngemm;
        if (i < ncopy) {
            int g;
            if (MODE == 0) g = (i < 475) ? 293 + i : 768 + (i - 475);
            else if (MODE == 1) g = (i < 57) ? 170 + i
                                 : (i < 153) ? 1152 + (i - 57)
                                             : 1002 + (i - 153);
            else g = (i < 66) ? 227 + i
                   : (i < 162) ? 1248 + (i - 66)
                               : 1077 + (i - 162);
            copy_chunk(g, s4b, s8b, s16b, bb);
        } else if (MODE == 0) {
            int j = i - ncopy;  // 0..4607 expert-weight converts
            int mat = j / 576, q = j % 576;
            int ci0 = (q % 24) * 32, co0 = (q / 24) * 32;
            const float* src = (mat < 4 ? ew1 : ew2) + (size_t)(mat & 3) * CCH * CCH;
            short* dst = (mat < 4 ? W1T : W2T) + (size_t)(mat & 3) * CCH * CCH;
            float* tile = (float*)lds;  // [32][33]
            int tx = t & 31, ty = t >> 5;
#pragma unroll
            for (int i4 = 0; i4 < 4; ++i4)
                tile[(ty + 8 * i4) * 33 + tx] =
                    src[(size_t)(ci0 + ty + 8 * i4) * CCH + co0 + tx];
            __syncthreads();
#pragma unroll
            for (int i4 = 0; i4 < 4; ++i4) {
                int co = co0 + ty + 8 * i4;
                dst[(size_t)co * CCH + ci0 + tx] = f2b(tile[tx * 33 + ty + 8 * i4]);
            }
        }
        return;
    }

    int cbk = bid % 6;
    int mt = bid / 6;
    int c0 = cbk * 128;
    int e = 0, ts = mt, cnt = 1 << 30, ofs = 0, mrow0 = 0;
    if (MODE == 0) {
        mrow0 = mt * 128;
    } else {
        e = mt >> 6;
        ts = mt & 63;
        int n0 = counts[0], n1 = counts[1], n2 = counts[2], n3 = counts[3];
        cnt = (e == 0) ? n0 : (e == 1) ? n1 : (e == 2) ? n2 : n3;
        if (ts * 128 >= cnt) return;
        ofs = (e > 0 ? n0 : 0) + (e > 1 ? n1 : 0) + (e > 2 ? n2 : 0);
    }

    int lane = t & 63, w = t >> 6;
    int wr = w >> 1, wc = w & 1;
    int lrow = lane & 15, lk8 = lane >> 4;

    const short* aS[4];
    const short* bS[4];
    const short* alS[2];
    const short* blS[2];
    int dA[4];

    if (MODE == 0) {
#pragma unroll
        for (int i = 0; i < 2; ++i) {
            int c = 2 * w + i;
            int row = c * 16 + lrow;
            int koff = lk8 * 8;
            aS[i]  = Ahp + (size_t)(mrow0 + row) * CCH + koff;
            alS[i] = Alp + (size_t)(mrow0 + row) * CCH + koff;
            bS[i]  = Bhp + (size_t)(c0 + row) * CCH + koff;
            blS[i] = Blp + (size_t)(c0 + row) * CCH + koff;
            dA[i] = c * 512;
        }
    } else {
        size_t eoff = (size_t)e * CCH * CCH;
#pragma unroll
        for (int i = 0; i < 4; ++i) {
            int c = 4 * w + i;
            int g = c >> 1, ph = c & 1;
            int row = g * 16 + lrow;
            int koff = ph * 32 + lk8 * 8;
            int pl = ts * 128 + row;
            int pc = pl < cnt ? pl : cnt - 1;
            int arow = (MODE == 1) ? perm[e * 8192 + pc] : (ofs + pc);
            aS[i] = Ahp + (size_t)arow * CCH + koff;
            bS[i] = Bhp + eoff + (size_t)(c0 + row) * CCH + koff;
            dA[i] = c * 512;
        }
    }

    f32x4 acc[4][4] = {};

    if (MODE == 0) {
        auto stage = [&](int b, int k0) {
            short* L = lds + b * 16384;
#pragma unroll
            for (int i = 0; i < 2; ++i) {
                gl16(aS[i] + k0, L + dA[i]);
                gl16(bS[i] + k0, L + 4096 + dA[i]);
                gl16(alS[i] + k0, L + 8192 + dA[i]);
                gl16(blS[i] + k0, L + 12288 + dA[i]);
            }
        };
        stage(0, 0);
        __syncthreads();
        for (int tt = 0; tt < 24; ++tt) {
            int cur = tt & 1;
            if (tt < 23) stage(cur ^ 1, (tt + 1) * 32);
            const short* L = lds + cur * 16384;
            short8v af[4], bf[4], xf[4];
#pragma unroll
            for (int m = 0; m < 4; ++m)
                af[m] = *(const short8v*)(L + ((wr * 4 + m) * 64 + lane) * 8);
#pragma unroll
            for (int n = 0; n < 4; ++n)
                bf[n] = *(const short8v*)(L + 4096 + ((wc * 4 + n) * 64 + lane) * 8);
#pragma unroll
            for (int m = 0; m < 4; ++m)
#pragma unroll
                for (int n = 0; n < 4; ++n)
                    acc[m][n] = __builtin_amdgcn_mfma_f32_16x16x32_bf16(af[m], bf[n], acc[m][n], 0, 0, 0);
#pragma unroll
            for (int n = 0; n < 4; ++n)
                xf[n] = *(const short8v*)(L + 12288 + ((wc * 4 + n) * 64 + lane) * 8);
#pragma unroll
            for (int m = 0; m < 4; ++m)
#pragma unroll
                for (int n = 0; n < 4; ++n)
                    acc[m][n] = __builtin_amdgcn_mfma_f32_16x16x32_bf16(af[m], xf[n], acc[m][n], 0, 0, 0);
#pragma unroll
            for (int m = 0; m < 4; ++m)
                xf[m] = *(const short8v*)(L + 8192 + ((wr * 4 + m) * 64 + lane) * 8);
#pragma unroll
            for (int m = 0; m < 4; ++m)
#pragma unroll
                for (int n = 0; n < 4; ++n)
                    acc[m][n] = __builtin_amdgcn_mfma_f32_16x16x32_bf16(xf[m], bf[n], acc[m][n], 0, 0, 0);
            __syncthreads();
        }
    } else {
        auto stage = [&](int b, int k0) {
            short* L = lds + b * 16384;
#pragma unroll
            for (int i = 0; i < 4; ++i) {
                gl16(aS[i] + k0, L + dA[i]);
                gl16(bS[i] + k0, L + 8192 + dA[i]);
            }
        };
        stage(0, 0);
        __syncthreads();
        for (int tt = 0; tt < 12; ++tt) {
            int cur = tt & 1;
            if (tt < 11) stage(cur ^ 1, (tt + 1) * 64);
            const short* L = lds + cur * 16384;
#pragma unroll
            for (int kk = 0; kk < 2; ++kk) {
                short8v af[4], bf[4];
#pragma unroll
                for (int m = 0; m < 4; ++m)
                    af[m] = *(const short8v*)(L + (((wr * 4 + m) * 2 + kk) * 64 + lane) * 8);
#pragma unroll
                for (int n = 0; n < 4; ++n)
                    bf[n] = *(const short8v*)(L + 8192 + (((wc * 4 + n) * 2 + kk) * 64 + lane) * 8);
#pragma unroll
                for (int m = 0; m < 4; ++m)
#pragma unroll
                    for (int n = 0; n < 4; ++n)
                        acc[m][n] = __builtin_amdgcn_mfma_f32_16x16x32_bf16(af[m], bf[n], acc[m][n], 0, 0, 0);
            }
            __syncthreads();
        }
    }

    int cl = lane & 15, rh = (lane >> 4) * 4;
    if (MODE == 0) {
        int cb2 = cbk * 2 + wc;
        float bv[4];
        float4 w2v[4];
#pragma unroll
        for (int n_ = 0; n_ < 4; ++n_) {
            int col = c0 + wc * 64 + n_ * 16 + cl;
            bv[n_] = bias[col];
            w2v[n_] = *(const float4*)(gw2 + col * 4);
        }
#pragma unroll
        for (int m = 0; m < 4; ++m) {
#pragma unroll
            for (int ri = 0; ri < 4; ++ri) {
                float s0 = 0.f, s1 = 0.f, s2 = 0.f, s3 = 0.f;
#pragma unroll
                for (int n_ = 0; n_ < 4; ++n_) {
                    float g = gelu_tanh(acc[m][n_][ri] + bv[n_]);
                    s0 = fmaf(g, w2v[n_].x, s0);
                    s1 = fmaf(g, w2v[n_].y, s1);
                    s2 = fmaf(g, w2v[n_].z, s2);
                    s3 = fmaf(g, w2v[n_].w, s3);
                }
#pragma unroll
                for (int off = 1; off < 16; off <<= 1) {
                    s0 += __shfl_xor(s0, off);
                    s1 += __shfl_xor(s1, off);
                    s2 += __shfl_xor(s2, off);
                    s3 += __shfl_xor(s3, off);
                }
                if (cl == 0) {
                    int row = mrow0 + wr * 64 + m * 16 + rh + ri;
                    float4 pv;
                    pv.x = s0; pv.y = s1; pv.z = s2; pv.w = s3;
                    *(float4*)(partial + (size_t)(cb2 * 8192 + row) * 4) = pv;
                }
            }
        }
    } else {
#pragma unroll
        for (int n = 0; n < 4; ++n) {
            int col = c0 + wc * 64 + n * 16 + cl;
            float bv = bias[e * CCH + col];
#pragma unroll
            for (int m = 0; m < 4; ++m) {
#pragma unroll
                for (int ri = 0; ri < 4; ++ri) {
                    int p = ts * 128 + wr * 64 + m * 16 + rh + ri;
                    if (p < cnt) {
                        float v = acc[m][n][ri] + bv;
                        if (MODE == 1) {
                            Hout[(size_t)(ofs + p) * CCH + col] = f2b(gelu_tanh(v));
                        } else {
                            int nn = perm[e * 8192 + p];
                            Yt[(size_t)nn * CCH + col] = v * gval[nn];
                        }
                    }
                }
            }
        }
    }
}

// sum 12 partial-logit slabs + b2 -> top-1 softmax gate; scatter directly into
// per-expert perm regions (counts double as cursors — no separate scatter pass)
__global__ __launch_bounds__(256) void k_route(const float* __restrict__ partial,
                                               const float* __restrict__ b2,
                                               int* __restrict__ perm,
                                               float* __restrict__ gval,
                                               int* __restrict__ counts) {
    int n = blockIdx.x * 256 + threadIdx.x;
    float l0 = b2[0], l1 = b2[1], l2 = b2[2], l3 = b2[3];
#pragma unroll
    for (int p = 0; p < 12; ++p) {
        float4 v = *(const float4*)(partial + ((size_t)p * 8192 + n) * 4);
        l0 += v.x; l1 += v.y; l2 += v.z; l3 += v.w;
    }
    int e = 0;
    float m = l0;
    if (l1 > m) { m = l1; e = 1; }
    if (l2 > m) { m = l2; e = 2; }
    if (l3 > m) { m = l3; e = 3; }
    float s = __expf(l0 - m) + __expf(l1 - m) + __expf(l2 - m) + __expf(l3 - m);
    gval[n] = 1.0f / s;
    int pos = atomicAdd(counts + e, 1);
    perm[e * 8192 + pos] = n;
}

// out32 = Yt (f32 token-major) + s32, both sides coalesced
__global__ __launch_bounds__(256) void k_untr(const float* __restrict__ Yt,
                                              const float* __restrict__ s32,
                                              float* __restrict__ out32) {
    __shared__ float tile[32][33];
    int b = blockIdx.z;
    int c0 = blockIdx.y * 32, hw0 = blockIdx.x * 32;
    int tx = threadIdx.x, ty = threadIdx.y;
#pragma unroll
    for (int i = 0; i < 4; ++i) {
        int hwl = ty + 8 * i;
        tile[hwl][tx] = Yt[(size_t)(b * 1024 + hw0 + hwl) * CCH + c0 + tx];
    }
    __syncthreads();
    const float* sp = s32 + (size_t)b * CCH * 1024;
    float* op = out32 + (size_t)b * CCH * 1024;
#pragma unroll
    for (int i = 0; i < 4; ++i) {
        size_t a = (size_t)(c0 + ty + 8 * i) * 1024 + hw0 + tx;
        op[a] = tile[tx][ty + 8 * i] + sp[a];
    }
}

extern "C" void kernel_launch(void* const* d_in, const int* in_sizes, int n_in,
                              void* d_out, int out_size, void* d_ws, size_t ws_size,
                              hipStream_t stream) {
    const float* s4  = (const float*)d_in[0];
    const float* s8  = (const float*)d_in[1];
    const float* s16 = (const float*)d_in[2];
    const float* s32 = (const float*)d_in[3];
    const float* gw1 = (const float*)d_in[4];
    const float* gb1 = (const float*)d_in[5];
    const float* gw2 = (const float*)d_in[6];
    const float* gb2 = (const float*)d_in[7];
    const float* ew1 = (const float*)d_in[8];
    const float* eb1 = (const float*)d_in[9];
    const float* ew2 = (const float*)d_in[10];
    const float* eb2 = (const float*)d_in[11];

    char* bb = (char*)d_out;
    float* Yt      = (float*)(bb + OFF_YT);
    short* Hh      = (short*)(bb + OFF_HH);
    short* W2T     = (short*)(bb + OFF_W2T);
    int*   iaux    = (int*)(bb + OFF_AUX);
    int*   perm    = iaux;              // 4 x 8192 (per-expert regions)
    int*   counts  = iaux + 32768;      // 4 (double as scatter cursors)
    float* gval    = (float*)(iaux + 32776);  // 8192
    float* partial = (float*)(bb + OFF_PART);
    short* Xl      = (short*)(bb + OFF_XL);
    short* GWh     = (short*)(bb + OFF_GWH);
    short* GWl     = (short*)(bb + OFF_GWL);
    short* Xh      = (short*)(bb + OFF_XH);
    short* W1T     = (short*)(bb + OFF_W1T);
    float* out32   = (float*)(bb + (size_t)1344 * CHUNK);

    k_prep<<<dim3(32, 24, 9), dim3(32, 8), 0, stream>>>(s32, gw1, Xh, Xl, GWh, GWl,
                                                        counts);
    // gate (split-bf16 GEMM + fused W2 partials) + 709 copies + 4608 ew converts
    k_mfma<0><<<384 + 709 + 4608, 256, 0, stream>>>(Xh, Xl, GWh, GWl, gb1, gw2,
                                                    perm, counts, gval, Yt, Hh,
                                                    partial, ew1, ew2, W1T, W2T,
                                                    (const char*)s4, (const char*)s8,
                                                    (const char*)s16, bb, 384, 709);
    k_route<<<32, 256, 0, stream>>>(partial, gb2, perm, gval, counts);
    // expert layer 1 + Xl/GW restores (57) + s16 first-half (96) + s8 (75)
    k_mfma<1><<<1536 + 228, 256, 0, stream>>>(Xh, Xl, W1T, GWl, eb1, gw2,
                                              perm, counts, gval, Yt, Hh,
                                              partial, ew1, ew2, W1T, W2T,
                                              (const char*)s4, (const char*)s8,
                                              (const char*)s16, bb, 1536, 228);
    // expert layer 2 + Xh/W1T restores (66) + s16 second-half (96) + s8 (75)
    k_mfma<2><<<1536 + 237, 256, 0, stream>>>(Hh, Xl, W2T, GWl, eb2, gw2,
                                              perm, counts, gval, Yt, Hh,
                                              partial, ew1, ew2, W1T, W2T,
                                              (const char*)s4, (const char*)s8,
                                              (const char*)s16, bb, 1536, 237);
    k_untr<<<dim3(32, 24, 8), dim3(32, 8), 0, stream>>>(Yt, s32, out32);
    // restore tail region [0,170) with real s4 data
    hipMemcpyAsync(bb, s4, (size_t)TAILBYTES, hipMemcpyDeviceToDevice, stream);
}

// Round 12
// 364.676 us; speedup vs baseline: 1.1345x; 1.1345x over previous
//
#include <hip/hip_runtime.h>
#include <cstddef>

#define CCH 768
#define CHUNK 262144u

// ---- d_out scratch carve (256 KiB chunks) — EXACT R10 layout ----
// tail [0,170): Yt(f32,96) Hh(48) W2T(18) aux+partial  -> final memcpy
// [170,227)  Xl, GWh, GWl (dead after gate)            -> restored in exp1
// [227,293)  Xh, W1T (dead after exp1)                 -> restored in exp2
// early s4 [293,768) + s8 [768,1152)                   -> restored in gate
// s16 [1152,1344): first 96 in exp1, last 96 in exp2
#define OFF_YT    0u
#define OFF_HH    25165824u
#define OFF_W2T   37748736u
#define OFF_AUX   42467328u
#define OFF_PART  42631424u
#define TAILBYTES 44564480u
#define OFF_XL    44564480u
#define OFF_GWH   57147392u
#define OFF_GWL   58327040u
#define OFF_XH    59506688u
#define OFF_W1T   72089600u

typedef __attribute__((ext_vector_type(8))) short short8v;
typedef __attribute__((ext_vector_type(4))) float f32x4;

__device__ __forceinline__ void gl16(const void* g, void* l) {
    __builtin_amdgcn_global_load_lds(
        (const __attribute__((address_space(1))) void*)g,
        (__attribute__((address_space(3))) void*)l, 16, 0, 0);
}

__device__ __forceinline__ void copy_chunk(int g, const char* s4b, const char* s8b,
                                           const char* s16b, char* bb) {
    const char* src = (g < 768) ? s4b + (size_t)g * CHUNK
                    : (g < 1152) ? s8b + (size_t)(g - 768) * CHUNK
                                 : s16b + (size_t)(g - 1152) * CHUNK;
    const uint4* s = (const uint4*)src;
    uint4* d = (uint4*)(bb + (size_t)g * CHUNK);
    int t = threadIdx.x;
#pragma unroll 8
    for (int it = 0; it < 64; ++it) d[it * 256 + t] = s[it * 256 + t];
}

__device__ __forceinline__ float gelu_tanh(float x) {
    // JAX default gelu (approximate=True)
    float u = 0.7978845608028654f * (x + 0.044715f * x * x * x);
    float e = __expf(2.0f * u);
    float t = 1.0f - 2.0f / (e + 1.0f);
    return 0.5f * x * (1.0f + t);
}

__device__ __forceinline__ short f2b(float f) {
    unsigned u = __float_as_uint(f);
    unsigned r = (u + 0x7FFFu + ((u >> 16) & 1u)) >> 16;
    return (short)r;
}

__device__ __forceinline__ float b2f(short s) {
    return __uint_as_float(((unsigned)(unsigned short)s) << 16);
}

// z<8: BCHW->token-major bf16 hi/lo transpose of s32. z==8: gate W1 hi/lo
// transposed convert. Also zeroes counts (which double as scatter cursors).
__global__ __launch_bounds__(256) void k_prep(const float* __restrict__ s32,
                                              const float* __restrict__ gw1,
                                              short* __restrict__ Xh,
                                              short* __restrict__ Xl,
                                              short* __restrict__ GWh,
                                              short* __restrict__ GWl,
                                              int* __restrict__ az) {
    int z = blockIdx.z;
    int tx = threadIdx.x, ty = threadIdx.y;
    if (z == 0 && blockIdx.x == 0 && blockIdx.y == 0 && ty == 0 && tx < 8)
        az[tx] = 0;
    __shared__ float tile[32][33];
    if (z < 8) {
        int c0 = blockIdx.y * 32, hw0 = blockIdx.x * 32;
        const float* s = s32 + (size_t)z * CCH * 1024;
#pragma unroll
        for (int i = 0; i < 4; ++i)
            tile[ty + 8 * i][tx] = s[(size_t)(c0 + ty + 8 * i) * 1024 + hw0 + tx];
        __syncthreads();
#pragma unroll
        for (int i = 0; i < 4; ++i) {
            int r = ty + 8 * i;
            int n = z * 1024 + hw0 + r;
            float v = tile[tx][r];
            short h = f2b(v);
            Xh[(size_t)n * CCH + c0 + tx] = h;
            Xl[(size_t)n * CCH + c0 + tx] = f2b(v - b2f(h));
        }
    } else {
        if (blockIdx.x >= 24) return;
        int ci0 = blockIdx.x * 32, co0 = blockIdx.y * 32;
#pragma unroll
        for (int i = 0; i < 4; ++i)
            tile[ty + 8 * i][tx] = gw1[(size_t)(ci0 + ty + 8 * i) * CCH + co0 + tx];
        __syncthreads();
#pragma unroll
        for (int i = 0; i < 4; ++i) {
            int co = co0 + ty + 8 * i;
            float v = tile[tx][ty + 8 * i];
            short h = f2b(v);
            GWh[(size_t)co * CCH + ci0 + tx] = h;
            GWl[(size_t)co * CCH + ci0 + tx] = f2b(v - b2f(h));
        }
    }
}

// 128x128-tile bf16 MFMA GEMM, 4 waves (64x64 quadrants), 2-phase
// double-buffered global_load_lds pipeline (R6/R10-proven core). Appended copy
// chunks per mode; MODE 0 additionally carries 4608 expert-weight converts.
// MODE 0: split-bf16: partial logits = gelu((Xh+Xl)@(GWh+GWl)^T + gb1) @ W2
// MODE 1: Hh[ofs+p] = f2b(gelu(Xh[perm_e] @ W1T^T + eb1))
// MODE 2: Yt[perm_e[p]] = (Hh @ W2T^T + eb2)*gval   (f32 token-major)
template <int MODE>
__global__ __launch_bounds__(256) void k_mfma(const short* __restrict__ Ahp,
                                              const short* __restrict__ Alp,
                                              const short* __restrict__ Bhp,
                                              const short* __restrict__ Blp,
                                              const float* __restrict__ bias,
                                              const float* __restrict__ gw2,
                                              const int* __restrict__ perm,
                                              const int* __restrict__ counts,
                                              const float* __restrict__ gval,
                                              float* __restrict__ Yt,
                                              short* __restrict__ Hout,
                                              float* __restrict__ partial,
                                              const float* __restrict__ ew1,
                                              const float* __restrict__ ew2,
                                              short* __restrict__ W1T,
                                              short* __restrict__ W2T,
                                              const char* __restrict__ s4b,
                                              const char* __restrict__ s8b,
                                              const char* __restrict__ s16b,
                                              char* __restrict__ bb,
                                              int ngemm, int ncopy) {
    __shared__ __align__(16) short lds[32768];
    int bid = blockIdx.x;
    int t = threadIdx.x;
    if (bid >= ngemm) {
        int i = bid - ngemm;
        if (i < ncopy) {
            int g;
            if (MODE == 0) g = (i < 475) ? 293 + i : 768 + (i - 475);
            else if (MODE == 1) g = (i < 57) ? 170 + i : 1152 + (i - 57);
            else g = (i < 66) ? 227 + i : 1248 + (i - 66);
            copy_chunk(g, s4b, s8b, s16b, bb);
        } else if (MODE == 0) {
            int j = i - ncopy;  // 0..4607 expert-weight converts
            int mat = j / 576, q = j % 576;
            int ci0 = (q % 24) * 32, co0 = (q / 24) * 32;
            const float* src = (mat < 4 ? ew1 : ew2) + (size_t)(mat & 3) * CCH * CCH;
            short* dst = (mat < 4 ? W1T : W2T) + (size_t)(mat & 3) * CCH * CCH;
            float* tile = (float*)lds;  // [32][33]
            int tx = t & 31, ty = t >> 5;
#pragma unroll
            for (int i4 = 0; i4 < 4; ++i4)
                tile[(ty + 8 * i4) * 33 + tx] =
                    src[(size_t)(ci0 + ty + 8 * i4) * CCH + co0 + tx];
            __syncthreads();
#pragma unroll
            for (int i4 = 0; i4 < 4; ++i4) {
                int co = co0 + ty + 8 * i4;
                dst[(size_t)co * CCH + ci0 + tx] = f2b(tile[tx * 33 + ty + 8 * i4]);
            }
        }
        return;
    }

    int cbk = bid % 6;
    int mt = bid / 6;
    int c0 = cbk * 128;
    int e = 0, ts = mt, cnt = 1 << 30, ofs = 0, mrow0 = 0;
    if (MODE == 0) {
        mrow0 = mt * 128;
    } else {
        e = mt >> 6;
        ts = mt & 63;
        int n0 = counts[0], n1 = counts[1], n2 = counts[2], n3 = counts[3];
        cnt = (e == 0) ? n0 : (e == 1) ? n1 : (e == 2) ? n2 : n3;
        if (ts * 128 >= cnt) return;
        ofs = (e > 0 ? n0 : 0) + (e > 1 ? n1 : 0) + (e > 2 ? n2 : 0);
    }

    int lane = t & 63, w = t >> 6;
    int wr = w >> 1, wc = w & 1;
    int lrow = lane & 15, lk8 = lane >> 4;

    const short* aS[4];
    const short* bS[4];
    const short* alS[2];
    const short* blS[2];
    int dA[4];

    if (MODE == 0) {
#pragma unroll
        for (int i = 0; i < 2; ++i) {
            int c = 2 * w + i;
            int row = c * 16 + lrow;
            int koff = lk8 * 8;
            aS[i]  = Ahp + (size_t)(mrow0 + row) * CCH + koff;
            alS[i] = Alp + (size_t)(mrow0 + row) * CCH + koff;
            bS[i]  = Bhp + (size_t)(c0 + row) * CCH + koff;
            blS[i] = Blp + (size_t)(c0 + row) * CCH + koff;
            dA[i] = c * 512;
        }
    } else {
        size_t eoff = (size_t)e * CCH * CCH;
#pragma unroll
        for (int i = 0; i < 4; ++i) {
            int c = 4 * w + i;
            int g = c >> 1, ph = c & 1;
            int row = g * 16 + lrow;
            int koff = ph * 32 + lk8 * 8;
            int pl = ts * 128 + row;
            int pc = pl < cnt ? pl : cnt - 1;
            int arow = (MODE == 1) ? perm[e * 8192 + pc] : (ofs + pc);
            aS[i] = Ahp + (size_t)arow * CCH + koff;
            bS[i] = Bhp + eoff + (size_t)(c0 + row) * CCH + koff;
            dA[i] = c * 512;
        }
    }

    f32x4 acc[4][4] = {};

    if (MODE == 0) {
        auto stage = [&](int b, int k0) {
            short* L = lds + b * 16384;
#pragma unroll
            for (int i = 0; i < 2; ++i) {
                gl16(aS[i] + k0, L + dA[i]);
                gl16(bS[i] + k0, L + 4096 + dA[i]);
                gl16(alS[i] + k0, L + 8192 + dA[i]);
                gl16(blS[i] + k0, L + 12288 + dA[i]);
            }
        };
        stage(0, 0);
        __syncthreads();
        for (int tt = 0; tt < 24; ++tt) {
            int cur = tt & 1;
            if (tt < 23) stage(cur ^ 1, (tt + 1) * 32);
            const short* L = lds + cur * 16384;
            short8v af[4], bf[4], xf[4];
#pragma unroll
            for (int m = 0; m < 4; ++m)
                af[m] = *(const short8v*)(L + ((wr * 4 + m) * 64 + lane) * 8);
#pragma unroll
            for (int n = 0; n < 4; ++n)
                bf[n] = *(const short8v*)(L + 4096 + ((wc * 4 + n) * 64 + lane) * 8);
#pragma unroll
            for (int m = 0; m < 4; ++m)
#pragma unroll
                for (int n = 0; n < 4; ++n)
                    acc[m][n] = __builtin_amdgcn_mfma_f32_16x16x32_bf16(af[m], bf[n], acc[m][n], 0, 0, 0);
#pragma unroll
            for (int n = 0; n < 4; ++n)
                xf[n] = *(const short8v*)(L + 12288 + ((wc * 4 + n) * 64 + lane) * 8);
#pragma unroll
            for (int m = 0; m < 4; ++m)
#pragma unroll
                for (int n = 0; n < 4; ++n)
                    acc[m][n] = __builtin_amdgcn_mfma_f32_16x16x32_bf16(af[m], xf[n], acc[m][n], 0, 0, 0);
#pragma unroll
            for (int m = 0; m < 4; ++m)
                xf[m] = *(const short8v*)(L + 8192 + ((wr * 4 + m) * 64 + lane) * 8);
#pragma unroll
            for (int m = 0; m < 4; ++m)
#pragma unroll
                for (int n = 0; n < 4; ++n)
                    acc[m][n] = __builtin_amdgcn_mfma_f32_16x16x32_bf16(xf[m], bf[n], acc[m][n], 0, 0, 0);
            __syncthreads();
        }
    } else {
        auto stage = [&](int b, int k0) {
            short* L = lds + b * 16384;
#pragma unroll
            for (int i = 0; i < 4; ++i) {
                gl16(aS[i] + k0, L + dA[i]);
                gl16(bS[i] + k0, L + 8192 + dA[i]);
            }
        };
        stage(0, 0);
        __syncthreads();
        for (int tt = 0; tt < 12; ++tt) {
            int cur = tt & 1;
            if (tt < 11) stage(cur ^ 1, (tt + 1) * 64);
            const short* L = lds + cur * 16384;
#pragma unroll
            for (int kk = 0; kk < 2; ++kk) {
                short8v af[4], bf[4];
#pragma unroll
                for (int m = 0; m < 4; ++m)
                    af[m] = *(const short8v*)(L + (((wr * 4 + m) * 2 + kk) * 64 + lane) * 8);
#pragma unroll
                for (int n = 0; n < 4; ++n)
                    bf[n] = *(const short8v*)(L + 8192 + (((wc * 4 + n) * 2 + kk) * 64 + lane) * 8);
#pragma unroll
                for (int m = 0; m < 4; ++m)
#pragma unroll
                    for (int n = 0; n < 4; ++n)
                        acc[m][n] = __builtin_amdgcn_mfma_f32_16x16x32_bf16(af[m], bf[n], acc[m][n], 0, 0, 0);
            }
            __syncthreads();
        }
    }

    int cl = lane & 15, rh = (lane >> 4) * 4;
    if (MODE == 0) {
        int cb2 = cbk * 2 + wc;
        float bv[4];
        float4 w2v[4];
#pragma unroll
        for (int n_ = 0; n_ < 4; ++n_) {
            int col = c0 + wc * 64 + n_ * 16 + cl;
            bv[n_] = bias[col];
            w2v[n_] = *(const float4*)(gw2 + col * 4);
        }
#pragma unroll
        for (int m = 0; m < 4; ++m) {
#pragma unroll
            for (int ri = 0; ri < 4; ++ri) {
                float s0 = 0.f, s1 = 0.f, s2 = 0.f, s3 = 0.f;
#pragma unroll
                for (int n_ = 0; n_ < 4; ++n_) {
                    float g = gelu_tanh(acc[m][n_][ri] + bv[n_]);
                    s0 = fmaf(g, w2v[n_].x, s0);
                    s1 = fmaf(g, w2v[n_].y, s1);
                    s2 = fmaf(g, w2v[n_].z, s2);
                    s3 = fmaf(g, w2v[n_].w, s3);
                }
#pragma unroll
                for (int off = 1; off < 16; off <<= 1) {
                    s0 += __shfl_xor(s0, off);
                    s1 += __shfl_xor(s1, off);
                    s2 += __shfl_xor(s2, off);
                    s3 += __shfl_xor(s3, off);
                }
                if (cl == 0) {
                    int row = mrow0 + wr * 64 + m * 16 + rh + ri;
                    float4 pv;
                    pv.x = s0; pv.y = s1; pv.z = s2; pv.w = s3;
                    *(float4*)(partial + (size_t)(cb2 * 8192 + row) * 4) = pv;
                }
            }
        }
    } else {
#pragma unroll
        for (int n = 0; n < 4; ++n) {
            int col = c0 + wc * 64 + n * 16 + cl;
            float bv = bias[e * CCH + col];
#pragma unroll
            for (int m = 0; m < 4; ++m) {
#pragma unroll
                for (int ri = 0; ri < 4; ++ri) {
                    int p = ts * 128 + wr * 64 + m * 16 + rh + ri;
                    if (p < cnt) {
                        float v = acc[m][n][ri] + bv;
                        if (MODE == 1) {
                            Hout[(size_t)(ofs + p) * CCH + col] = f2b(gelu_tanh(v));
                        } else {
                            int nn = perm[e * 8192 + p];
                            Yt[(size_t)nn * CCH + col] = v * gval[nn];
                        }
                    }
                }
            }
        }
    }
}

// sum 12 partial-logit slabs + b2 -> top-1 softmax gate; scatter directly into
// per-expert perm regions (counts double as cursors — no separate scatter pass)
__global__ __launch_bounds__(256) void k_route(const float* __restrict__ partial,
                                               const float* __restrict__ b2,
                                               int* __restrict__ perm,
                                               float* __restrict__ gval,
                                               int* __restrict__ counts) {
    int n = blockIdx.x * 256 + threadIdx.x;
    float l0 = b2[0], l1 = b2[1], l2 = b2[2], l3 = b2[3];
#pragma unroll
    for (int p = 0; p < 12; ++p) {
        float4 v = *(const float4*)(partial + ((size_t)p * 8192 + n) * 4);
        l0 += v.x; l1 += v.y; l2 += v.z; l3 += v.w;
    }
    int e = 0;
    float m = l0;
    if (l1 > m) { m = l1; e = 1; }
    if (l2 > m) { m = l2; e = 2; }
    if (l3 > m) { m = l3; e = 3; }
    float s = __expf(l0 - m) + __expf(l1 - m) + __expf(l2 - m) + __expf(l3 - m);
    gval[n] = 1.0f / s;
    int pos = atomicAdd(counts + e, 1);
    perm[e * 8192 + pos] = n;
}

// out32 = Yt (f32 token-major) + s32, both sides coalesced
__global__ __launch_bounds__(256) void k_untr(const float* __restrict__ Yt,
                                              const float* __restrict__ s32,
                                              float* __restrict__ out32) {
    __shared__ float tile[32][33];
    int b = blockIdx.z;
    int c0 = blockIdx.y * 32, hw0 = blockIdx.x * 32;
    int tx = threadIdx.x, ty = threadIdx.y;
#pragma unroll
    for (int i = 0; i < 4; ++i) {
        int hwl = ty + 8 * i;
        tile[hwl][tx] = Yt[(size_t)(b * 1024 + hw0 + hwl) * CCH + c0 + tx];
    }
    __syncthreads();
    const float* sp = s32 + (size_t)b * CCH * 1024;
    float* op = out32 + (size_t)b * CCH * 1024;
#pragma unroll
    for (int i = 0; i < 4; ++i) {
        size_t a = (size_t)(c0 + ty + 8 * i) * 1024 + hw0 + tx;
        op[a] = tile[tx][ty + 8 * i] + sp[a];
    }
}

extern "C" void kernel_launch(void* const* d_in, const int* in_sizes, int n_in,
                              void* d_out, int out_size, void* d_ws, size_t ws_size,
                              hipStream_t stream) {
    const float* s4  = (const float*)d_in[0];
    const float* s8  = (const float*)d_in[1];
    const float* s16 = (const float*)d_in[2];
    const float* s32 = (const float*)d_in[3];
    const float* gw1 = (const float*)d_in[4];
    const float* gb1 = (const float*)d_in[5];
    const float* gw2 = (const float*)d_in[6];
    const float* gb2 = (const float*)d_in[7];
    const float* ew1 = (const float*)d_in[8];
    const float* eb1 = (const float*)d_in[9];
    const float* ew2 = (const float*)d_in[10];
    const float* eb2 = (const float*)d_in[11];

    char* bb = (char*)d_out;
    float* Yt      = (float*)(bb + OFF_YT);
    short* Hh      = (short*)(bb + OFF_HH);
    short* W2T     = (short*)(bb + OFF_W2T);
    int*   iaux    = (int*)(bb + OFF_AUX);
    int*   perm    = iaux;              // 4 x 8192 (per-expert regions)
    int*   counts  = iaux + 32768;      // 4 (double as scatter cursors)
    float* gval    = (float*)(iaux + 32776);  // 8192
    float* partial = (float*)(bb + OFF_PART);
    short* Xl      = (short*)(bb + OFF_XL);
    short* GWh     = (short*)(bb + OFF_GWH);
    short* GWl     = (short*)(bb + OFF_GWL);
    short* Xh      = (short*)(bb + OFF_XH);
    short* W1T     = (short*)(bb + OFF_W1T);
    float* out32   = (float*)(bb + (size_t)1344 * CHUNK);

    k_prep<<<dim3(32, 24, 9), dim3(32, 8), 0, stream>>>(s32, gw1, Xh, Xl, GWh, GWl,
                                                        counts);
    // gate (split-bf16 GEMM + fused W2 partials) + 859 copies + 4608 ew converts
    k_mfma<0><<<384 + 859 + 4608, 256, 0, stream>>>(Xh, Xl, GWh, GWl, gb1, gw2,
                                                    perm, counts, gval, Yt, Hh,
                                                    partial, ew1, ew2, W1T, W2T,
                                                    (const char*)s4, (const char*)s8,
                                                    (const char*)s16, bb, 384, 859);
    k_route<<<32, 256, 0, stream>>>(partial, gb2, perm, gval, counts);
    // expert layer 1 + Xl/GW restores (57) + s16 first-half (96)
    k_mfma<1><<<1536 + 153, 256, 0, stream>>>(Xh, Xl, W1T, GWl, eb1, gw2,
                                              perm, counts, gval, Yt, Hh,
                                              partial, ew1, ew2, W1T, W2T,
                                              (const char*)s4, (const char*)s8,
                                              (const char*)s16, bb, 1536, 153);
    // expert layer 2 + Xh/W1T restores (66) + s16 second-half (96)
    k_mfma<2><<<1536 + 162, 256, 0, stream>>>(Hh, Xl, W2T, GWl, eb2, gw2,
                                              perm, counts, gval, Yt, Hh,
                                              partial, ew1, ew2, W1T, W2T,
                                              (const char*)s4, (const char*)s8,
                                              (const char*)s16, bb, 1536, 162);
    k_untr<<<dim3(32, 24, 8), dim3(32, 8), 0, stream>>>(Yt, s32, out32);
    // restore tail region [0,170) with real s4 data
    hipMemcpyAsync(bb, s4, (size_t)TAILBYTES, hipMemcpyDeviceToDevice, stream);
}